// Round 1
// 853.470 us; speedup vs baseline: 1.0287x; 1.0287x over previous
//
#include <hip/hip_runtime.h>
#include <cstdint>

#define D_MODEL 2048
#define T_SEQ   2048
#define BATCH   2
#define NHEAD   16
#define HDIM    128
#define FFDIM   4096
#define NTOK    4096  // B*T

using bf16_t = __bf16;
typedef __attribute__((ext_vector_type(8))) __bf16 bf16x8;
typedef __attribute__((ext_vector_type(4))) __bf16 bf16x4;
typedef __attribute__((ext_vector_type(4))) float  f32x4;

typedef __attribute__((address_space(1))) void as1_void;
typedef __attribute__((address_space(3))) void as3_void;

// async global->LDS, 16B per lane; LDS dest is wave-uniform base + lane*16
__device__ __forceinline__ void async_copy16(const void* g, void* lds) {
  __builtin_amdgcn_global_load_lds((as1_void*)(uintptr_t)g,
                                   (as3_void*)(uint32_t)(uintptr_t)lds,
                                   16, 0, 0);
}

// Packed tile layout for GEMM operands: [n>>7][k>>5][chunk=kg*128+m][8 elems]
// (chunk order == GEMM LDS layout, so staging is a linear 8KB copy.)
__device__ __forceinline__ size_t packidx(int n, int kc, int nkt) {
  // kc = 8-elem chunk index within the row's K dimension
  int kt = kc >> 2, kg = kc & 3;
  return (((size_t)(n >> 7) * nkt + kt) << 9) + (kg << 7) + (n & 127);
}

// ------------- all 5 weight fp32->bf16 conversions + packing, ONE kernel -------------
// chunk counts (8 elems each)
#define NQ 1572864   // qkv  6144x2048
#define NO 524288    // o    2048x2048
#define NG 1048576   // gate 4096x2048
#define NU 1048576   // up   4096x2048
#define ND 1048576   // down 2048x4096
#define TOTC (NQ + NO + NG + NU + ND)
__global__ __launch_bounds__(256) void f2b_all_kernel(
    const float* __restrict__ s0, const float* __restrict__ s1,
    const float* __restrict__ s2, const float* __restrict__ s3,
    const float* __restrict__ s4,
    bf16_t* __restrict__ d0, bf16_t* __restrict__ d1,
    bf16_t* __restrict__ dgu, bf16_t* __restrict__ d4) {
  int c = blockIdx.x * 256 + threadIdx.x;
  const int stride = gridDim.x * 256;
  for (; c < TOTC; c += stride) {
    const float* src; bf16_t* dst; size_t didx; int sf4;
    if (c < NQ) {                       // qkv: K=2048, nkt=64
      int n = c >> 8, kc = c & 255;
      src = s0; sf4 = n * 512 + kc * 2;
      dst = d0; didx = packidx(n, kc, 64);
    } else if (c < NQ + NO) {           // o: K=2048
      int lc = c - NQ, n = lc >> 8, kc = lc & 255;
      src = s1; sf4 = n * 512 + kc * 2;
      dst = d1; didx = packidx(n, kc, 64);
    } else if (c < NQ + NO + NG) {      // gate -> interleaved n'
      int lc = c - NQ - NO, g = lc >> 8, kc = lc & 255;
      int n2 = ((g >> 4) << 5) + (g & 15);
      src = s2; sf4 = g * 512 + kc * 2;
      dst = dgu; didx = packidx(n2, kc, 64);
    } else if (c < NQ + NO + NG + NU) { // up -> interleaved n'
      int lc = c - NQ - NO - NG, u = lc >> 8, kc = lc & 255;
      int n2 = ((u >> 4) << 5) + 16 + (u & 15);
      src = s3; sf4 = u * 512 + kc * 2;
      dst = dgu; didx = packidx(n2, kc, 64);
    } else {                            // down: K=4096, nkt=128
      int lc = c - NQ - NO - NG - NU, n = lc >> 9, kc = lc & 511;
      src = s4; sf4 = n * 1024 + kc * 2;
      dst = d4; didx = packidx(n, kc, 128);
    }
    float4 v0 = ((const float4*)src)[sf4];
    float4 v1 = ((const float4*)src)[sf4 + 1];
    bf16x8 r;
    r[0] = (bf16_t)v0.x; r[1] = (bf16_t)v0.y; r[2] = (bf16_t)v0.z; r[3] = (bf16_t)v0.w;
    r[4] = (bf16_t)v1.x; r[5] = (bf16_t)v1.y; r[6] = (bf16_t)v1.z; r[7] = (bf16_t)v1.w;
    *(bf16x8*)(dst + didx * 8) = r;
  }
}

// ------- RMSNorm * norm_w * gamma + beta -> bf16 PACKED (row = 2048, K-tiles) -------
__global__ __launch_bounds__(256) void rmsnorm_kernel(const float* __restrict__ x,
                                                      const float* __restrict__ nw,
                                                      const float* __restrict__ gamma,
                                                      const float* __restrict__ beta,
                                                      bf16_t* __restrict__ out) {
  const int row = blockIdx.x;
  const int t = threadIdx.x;
  const float* xr = x + (size_t)row * D_MODEL;
  float4 va = ((const float4*)xr)[2 * t];
  float4 vb = ((const float4*)xr)[2 * t + 1];
  float ss = va.x*va.x + va.y*va.y + va.z*va.z + va.w*va.w
           + vb.x*vb.x + vb.y*vb.y + vb.z*vb.z + vb.w*vb.w;
#pragma unroll
  for (int off = 1; off < 64; off <<= 1) ss += __shfl_xor(ss, off, 64);
  __shared__ float sred[4];
  if ((t & 63) == 0) sred[t >> 6] = ss;
  __syncthreads();
  float tot = sred[0] + sred[1] + sred[2] + sred[3];
  float inv = rsqrtf(tot * (1.0f / D_MODEL) + 1.1920929e-07f);
  const int c0 = t * 8;
  float a8[8] = {va.x, va.y, va.z, va.w, vb.x, vb.y, vb.z, vb.w};
  bf16x8 r;
#pragma unroll
  for (int j = 0; j < 8; ++j)
    r[j] = (bf16_t)(a8[j] * inv * nw[c0 + j] * gamma[c0 + j] + beta[c0 + j]);
  *(bf16x8*)(out + packidx(row, t, 64) * 8) = r;
}

// ---------------- GEMM: C(M,N) = A(M,K) @ Bw(N,K)^T, bf16 MFMA ----------------
// A, Bw in PACKED tile layout -> staging is a linear coalesced 8KB stream/tile.
// 128x128 tile, BK=32, double-buffered LDS, ONE barrier per K-iter.
// EPI: 0 = store bf16 row-major; 1 = +aux(fp32) -> fp32 row-major;
//      4 = fused silu(gate)*up -> bf16 PACKED for the down GEMM (nkt=128)
template <int EPI>
__global__ __launch_bounds__(256) void gemm_kernel(const bf16_t* __restrict__ A,
                                                   const bf16_t* __restrict__ Bw,
                                                   int M, int N, int K,
                                                   void* out, const void* aux) {
  __shared__ alignas(16) bf16_t As[2][4][128][8];  // 2 x 8KB
  __shared__ alignas(16) bf16_t Bs[2][4][128][8];
  const int tid = threadIdx.x;
  const int wave = tid >> 6, lane = tid & 63;
  const int quad = lane >> 4, l16 = lane & 15;
  const int bx = blockIdx.x, by = blockIdx.y;
  const int wr = (wave >> 1) * 64, wc = (wave & 1) * 64;
  const int rowA0 = by * 128, colB0 = bx * 128;

  const f32x4 fzero = {0.f, 0.f, 0.f, 0.f};
  f32x4 acc[4][4];
#pragma unroll
  for (int i = 0; i < 4; ++i)
#pragma unroll
    for (int j = 0; j < 4; ++j) acc[i][j] = fzero;

  const int nk = K >> 5;
  // packed tile bases; thread stages chunks tid and tid+256 (16B each)
  const bf16_t* a0 = A + ((size_t)by * nk << 12) + tid * 8;
  const bf16_t* a1 = a0 + 2048;
  const bf16_t* b0 = Bw + ((size_t)bx * nk << 12) + tid * 8;
  const bf16_t* b1 = b0 + 2048;
  char* ldsA0 = (char*)As + (wave * 64) * 16;         // + buf*8192
  char* ldsA1 = (char*)As + (256 + wave * 64) * 16;
  char* ldsB0 = (char*)Bs + (wave * 64) * 16;
  char* ldsB1 = (char*)Bs + (256 + wave * 64) * 16;

  // prologue: loads for kt=0 into buf 0
  async_copy16(a0, ldsA0);
  async_copy16(a1, ldsA1);
  async_copy16(b0, ldsB0);
  async_copy16(b1, ldsB1);
  a0 += 4096; a1 += 4096; b0 += 4096; b1 += 4096;

  for (int kt = 0; kt < nk; ++kt) {
    __syncthreads();  // drains loads for buf[cur], issued one compute-phase ago
    const int cur = kt & 1;
    if (kt + 1 < nk) {
      const int nxt = 8192 * (1 - cur);
      async_copy16(a0, ldsA0 + nxt);
      async_copy16(a1, ldsA1 + nxt);
      async_copy16(b0, ldsB0 + nxt);
      async_copy16(b1, ldsB1 + nxt);
      a0 += 4096; a1 += 4096; b0 += 4096; b1 += 4096;
    }
    bf16x8 af[4], bfr[4];
#pragma unroll
    for (int mi = 0; mi < 4; ++mi)
      af[mi] = *(const bf16x8*)&As[cur][quad][wr + mi * 16 + l16][0];
#pragma unroll
    for (int ni = 0; ni < 4; ++ni)
      bfr[ni] = *(const bf16x8*)&Bs[cur][quad][wc + ni * 16 + l16][0];
#pragma unroll
    for (int mi = 0; mi < 4; ++mi)
#pragma unroll
      for (int ni = 0; ni < 4; ++ni)
        acc[mi][ni] = __builtin_amdgcn_mfma_f32_16x16x32_bf16(af[mi], bfr[ni],
                                                              acc[mi][ni], 0, 0, 0);
  }

  // epilogue: C row = quad*4+reg, col = l16 (m89-verified)
  if (EPI == 4) {
    // ni even = gate, ni odd = up for the same 16 ff cols; write PACKED (nkt=128)
#pragma unroll
    for (int mi = 0; mi < 4; ++mi) {
#pragma unroll
      for (int r = 0; r < 4; ++r) {
        const int row = rowA0 + wr + mi * 16 + quad * 4 + r;
        const int rt = row >> 7, m = row & 127;
#pragma unroll
        for (int p = 0; p < 2; ++p) {
          float g = acc[mi][2 * p][r];
          float u = acc[mi][2 * p + 1][r];
          float sv = g / (1.0f + __expf(-g));
          const int ffcol = bx * 64 + (wc >> 1) + l16 + p * 16;
          const int kt2 = ffcol >> 5, kg2 = (ffcol >> 3) & 3, e = ffcol & 7;
          const size_t idx =
              (((((size_t)rt * 128 + kt2) << 9) + (kg2 << 7) + m) << 3) + e;
          ((bf16_t*)out)[idx] = (bf16_t)(sv * u);
        }
      }
    }
  } else {
#pragma unroll
    for (int mi = 0; mi < 4; ++mi) {
#pragma unroll
      for (int r = 0; r < 4; ++r) {
        const int row = rowA0 + wr + mi * 16 + quad * 4 + r;
        const size_t base = (size_t)row * N;
#pragma unroll
        for (int ni = 0; ni < 4; ++ni) {
          const int col = colB0 + wc + ni * 16 + l16;
          const size_t idx = base + col;
          float v = acc[mi][ni][r];
          if (EPI == 0) {
            ((bf16_t*)out)[idx] = (bf16_t)v;
          } else {
            ((float*)out)[idx] = v + ((const float*)aux)[idx];
          }
        }
      }
    }
  }
}

// ---------------- V transpose: qkv_b V-part -> vt[bh][d][t] ----------------
__global__ __launch_bounds__(256) void vtrans_kernel(const bf16_t* __restrict__ qkv,
                                                     bf16_t* __restrict__ vt) {
  const int bh = blockIdx.y;
  const int b = bh >> 4, h = bh & 15;
  const int t0 = blockIdx.x << 6;
  const int tid = threadIdx.x;
  __shared__ bf16_t tile[64][136];  // pad 8 el: row stride 272B == 4 banks offset
#pragma unroll
  for (int r = 0; r < 4; ++r) {
    int ci = r * 256 + tid;
    int t = ci >> 4, dc = ci & 15;
    bf16x8 v = *(const bf16x8*)(qkv + (size_t)(b * T_SEQ + t0 + t) * 6144 + 4096 +
                                h * HDIM + dc * 8);
    *(bf16x8*)&tile[t][dc * 8] = v;
  }
  __syncthreads();
#pragma unroll
  for (int r = 0; r < 4; ++r) {
    int ci = r * 256 + tid;
    int d = ci >> 3, ts = ci & 7;
    bf16x8 o;
#pragma unroll
    for (int j = 0; j < 8; ++j) o[j] = tile[ts * 8 + j][d];
    *(bf16x8*)(vt + ((size_t)bh * HDIM + d) * T_SEQ + t0 + ts * 8) = o;
  }
}

// ---------------- causal flash attention, 64-row Q tile, 4 waves ----------------
// qkv: [b][t][i*2048 + h*128 + d]; vt: [bh][d][t]; out: PACKED (o-proj A, nkt=64)
// v2: double-buffered K/V staging — ONE barrier per K-tile, loads for kt+1 in
// flight under compute of kt (same schedule as gemm_kernel). Staging address
// math hoisted to incremented pointers.
__global__ __launch_bounds__(256) void attn_kernel(const bf16_t* __restrict__ qkv,
                                                   const bf16_t* __restrict__ vt,
                                                   bf16_t* __restrict__ out) {
  const int bh = blockIdx.y;
  const int b = bh >> 4, h = bh & 15;
  const int qt = gridDim.x - 1 - blockIdx.x;  // big tiles dispatch first
  const int q0 = qt << 6;
  const int tid = threadIdx.x;
  const int wave = tid >> 6, lane = tid & 63;
  const int quad = lane >> 4, l16 = lane & 15;

  // K tile: 16B chunks, chunk(t,c) at index t*16 + (c ^ (t&15))   (c = d>>3)
  __shared__ alignas(16) bf16_t Ks[2][64 * 128];
  // V^T tile: chunk(d,tc) at index d*8 + (tc ^ (d&7))             (tc = t>>3)
  __shared__ alignas(16) bf16_t VTs[2][128 * 64];
  // P per wave: [16 rows][68] (136B stride: writes hit 4 disjoint 32B windows)
  __shared__ bf16_t Ps[4][16][68];

  // Q fragments straight from global (one-time)
  const size_t qbase = (size_t)(b * T_SEQ + q0 + wave * 16 + l16) * 6144 + h * HDIM;
  bf16x8 qf[4];
#pragma unroll
  for (int kk = 0; kk < 4; ++kk)
    qf[kk] = *(const bf16x8*)(qkv + qbase + kk * 32 + quad * 8);

  // staging source pointers (per-lane), advanced one K-tile per stage
  const bf16_t* gK[4];
  const bf16_t* gV[4];
#pragma unroll
  for (int c = 0; c < 4; ++c) {
    int ci = c * 256 + tid;
    int t = ci >> 4, dcs = ci & 15;
    int dc = dcs ^ (t & 15);
    gK[c] = qkv + (size_t)(b * T_SEQ + t) * 6144 + 2048 + h * HDIM + dc * 8;
    int d = ci >> 3, tcs = ci & 7;
    int tc = tcs ^ (d & 7);
    gV[c] = vt + ((size_t)bh * HDIM + d) * T_SEQ + tc * 8;
  }
  char* ldsK = (char*)Ks + wave * 1024;  // + buf*16384 + c*4096
  char* ldsV = (char*)VTs + wave * 1024;

  auto stage = [&](int buf) {
#pragma unroll
    for (int c = 0; c < 4; ++c) {
      async_copy16(gK[c], ldsK + buf * 16384 + c * 4096);
      gK[c] += 64 * 6144;
    }
#pragma unroll
    for (int c = 0; c < 4; ++c) {
      async_copy16(gV[c], ldsV + buf * 16384 + c * 4096);
      gV[c] += 64;
    }
  };

  const f32x4 fzero = {0.f, 0.f, 0.f, 0.f};
  f32x4 o[8];
#pragma unroll
  for (int i = 0; i < 8; ++i) o[i] = fzero;
  float mrow[4] = {-3.0e38f, -3.0e38f, -3.0e38f, -3.0e38f};
  float lrow[4] = {0.f, 0.f, 0.f, 0.f};

  const float sc = 0.08838834764831845f;  // 1/sqrt(128)
  const int ktmax = qt;

  // prologue: stage tile 0 into buf 0
  stage(0);

  for (int kt = 0; kt <= ktmax; ++kt) {
    const int cur = kt & 1;
    // barrier: (a) implicit vmcnt(0) drains buf[cur] loads issued last iter;
    // (b) all waves done reading buf[1-cur] from previous compute phase.
    __syncthreads();
    if (kt < ktmax) stage(1 - cur);  // in flight under this iter's compute

    const bf16_t* Kc = &Ks[cur][0];
    const bf16_t* Vc = &VTs[cur][0];

    // S = Q @ K^T (wave strip: 16 q-rows x 64 k-cols)
    f32x4 s[4];
#pragma unroll
    for (int nt = 0; nt < 4; ++nt) {
      s[nt] = fzero;
#pragma unroll
      for (int kk = 0; kk < 4; ++kk) {
        int tK = nt * 16 + l16;
        int cK = kk * 4 + quad;
        bf16x8 kf = *(const bf16x8*)(Kc + (tK * 16 + (cK ^ l16)) * 8);
        s[nt] = __builtin_amdgcn_mfma_f32_16x16x32_bf16(qf[kk], kf, s[nt], 0, 0, 0);
      }
    }

    const int qr0 = q0 + wave * 16 + quad * 4;
    float alpha[4];
    const bool diag = (kt == ktmax);
#pragma unroll
    for (int r = 0; r < 4; ++r) {
      const int qr = qr0 + r;
      float mx = -3.0e38f;
#pragma unroll
      for (int nt = 0; nt < 4; ++nt) {
        float v = s[nt][r] * sc;
        if (diag) {
          int kc = kt * 64 + nt * 16 + l16;
          v = (kc <= qr) ? v : -3.0e38f;
        }
        s[nt][r] = v;
        mx = fmaxf(mx, v);
      }
#pragma unroll
      for (int off = 1; off < 16; off <<= 1) mx = fmaxf(mx, __shfl_xor(mx, off, 16));
      float mnew = fmaxf(mrow[r], mx);
      alpha[r] = __expf(mrow[r] - mnew);
      mrow[r] = mnew;
      float rs = 0.f;
#pragma unroll
      for (int nt = 0; nt < 4; ++nt) {
        float pv = __expf(s[nt][r] - mnew);
        s[nt][r] = pv;
        rs += pv;
      }
#pragma unroll
      for (int off = 1; off < 16; off <<= 1) rs += __shfl_xor(rs, off, 16);
      lrow[r] = lrow[r] * alpha[r] + rs;
    }

    // rescale O, round-trip P through LDS (C-layout -> A-layout)
#pragma unroll
    for (int i = 0; i < 8; ++i)
#pragma unroll
      for (int r = 0; r < 4; ++r) o[i][r] *= alpha[r];
#pragma unroll
    for (int nt = 0; nt < 4; ++nt)
#pragma unroll
      for (int r = 0; r < 4; ++r)
        Ps[wave][quad * 4 + r][nt * 16 + l16] = (bf16_t)s[nt][r];

    // O += P @ V   (pf: 2x ds_read_b64 conflict-free; vf: swizzled b128)
#pragma unroll
    for (int kk2 = 0; kk2 < 2; ++kk2) {
      const bf16_t* prow = &Ps[wave][l16][kk2 * 32 + quad * 8];
      bf16x4 p0 = *(const bf16x4*)prow;
      bf16x4 p1 = *(const bf16x4*)(prow + 4);
      bf16x8 pf;
#pragma unroll
      for (int j = 0; j < 4; ++j) { pf[j] = p0[j]; pf[4 + j] = p1[j]; }
#pragma unroll
      for (int nt2 = 0; nt2 < 8; ++nt2) {
        int dV = nt2 * 16 + l16;
        int tcV = kk2 * 4 + quad;
        bf16x8 vf = *(const bf16x8*)(Vc + (dV * 8 + (tcV ^ (dV & 7))) * 8);
        o[nt2] = __builtin_amdgcn_mfma_f32_16x16x32_bf16(pf, vf, o[nt2], 0, 0, 0);
      }
    }
  }

  float rl[4];
#pragma unroll
  for (int r = 0; r < 4; ++r) rl[r] = 1.0f / lrow[r];
#pragma unroll
  for (int nt2 = 0; nt2 < 8; ++nt2) {
#pragma unroll
    for (int r = 0; r < 4; ++r) {
      const int gt = b * T_SEQ + q0 + wave * 16 + quad * 4 + r;
      const int mt = gt >> 7, m = gt & 127;
      const int col = h * HDIM + nt2 * 16 + l16;
      const int kt2 = col >> 5, kg2 = (col >> 3) & 3, e = col & 7;
      const size_t idx = (((((size_t)mt * 64 + kt2) << 9) + (kg2 << 7) + m) << 3) + e;
      out[idx] = (bf16_t)(o[nt2][r] * rl[r]);
    }
  }
}

extern "C" void kernel_launch(void* const* d_in, const int* in_sizes, int n_in,
                              void* d_out, int out_size, void* d_ws, size_t ws_size,
                              hipStream_t stream) {
  const float* x      = (const float*)d_in[0];
  const float* gamma  = (const float*)d_in[1];
  const float* beta   = (const float*)d_in[2];
  const float* qkv_w  = (const float*)d_in[3];
  const float* o_w    = (const float*)d_in[4];
  const float* gate_w = (const float*)d_in[5];
  const float* up_w   = (const float*)d_in[6];
  const float* down_w = (const float*)d_in[7];
  const float* n1w    = (const float*)d_in[8];
  const float* n2w    = (const float*)d_in[9];
  float* out = (float*)d_out;

  char* p = (char*)d_ws;
  bf16_t* qkv_wb  = (bf16_t*)p; p += (size_t)3 * D_MODEL * D_MODEL * 2;
  bf16_t* o_wb    = (bf16_t*)p; p += (size_t)D_MODEL * D_MODEL * 2;
  bf16_t* gu_wb   = (bf16_t*)p; p += (size_t)2 * FFDIM * D_MODEL * 2;  // interleaved+packed
  bf16_t* down_wb = (bf16_t*)p; p += (size_t)D_MODEL * FFDIM * 2;
  bf16_t* h_b     = (bf16_t*)p; p += (size_t)NTOK * D_MODEL * 2;   // packed; reused for h2
  bf16_t* qkv_b   = (bf16_t*)p; p += (size_t)NTOK * 3 * D_MODEL * 2;
  bf16_t* attn_b  = (bf16_t*)p; p += (size_t)NTOK * D_MODEL * 2;   // packed
  float*  x1      = (float*)p;  p += (size_t)NTOK * D_MODEL * 4;
  bf16_t* g_b     = (bf16_t*)p; p += (size_t)NTOK * FFDIM * 2;     // packed silu(g)*u
  bf16_t* vt_b    = g_b;  // V^T overlaps g_b: lifetimes disjoint (attn vs FFN phase)

  dim3 blk(256);
  // all weight conversions + packing in one launch
  f2b_all_kernel<<<dim3(2048), blk, 0, stream>>>(
      qkv_w, o_w, gate_w, up_w, down_w,
      qkv_wb, o_wb, gu_wb, down_wb);

  // attention sub-block
  rmsnorm_kernel<<<dim3(NTOK), blk, 0, stream>>>(x, n1w, gamma, beta, h_b);
  gemm_kernel<0><<<dim3(3 * D_MODEL / 128, NTOK / 128), blk, 0, stream>>>(
      h_b, qkv_wb, NTOK, 3 * D_MODEL, D_MODEL, qkv_b, nullptr);
  vtrans_kernel<<<dim3(T_SEQ / 64, BATCH * NHEAD), blk, 0, stream>>>(qkv_b, vt_b);
  attn_kernel<<<dim3(T_SEQ / 64, BATCH * NHEAD), blk, 0, stream>>>(qkv_b, vt_b, attn_b);
  gemm_kernel<1><<<dim3(D_MODEL / 128, NTOK / 128), blk, 0, stream>>>(
      attn_b, o_wb, NTOK, D_MODEL, D_MODEL, x1, x);

  // FFN sub-block (gate+up fused into one GEMM, N=8192 interleaved)
  rmsnorm_kernel<<<dim3(NTOK), blk, 0, stream>>>(x1, n2w, gamma, beta, h_b);
  gemm_kernel<4><<<dim3(2 * FFDIM / 128, NTOK / 128), blk, 0, stream>>>(
      h_b, gu_wb, NTOK, 2 * FFDIM, D_MODEL, g_b, nullptr);
  gemm_kernel<1><<<dim3(D_MODEL / 128, NTOK / 128), blk, 0, stream>>>(
      g_b, down_wb, NTOK, D_MODEL, FFDIM, out, x1);
}

// Round 2
// 815.264 us; speedup vs baseline: 1.0770x; 1.0469x over previous
//
#include <hip/hip_runtime.h>
#include <cstdint>

#define D_MODEL 2048
#define T_SEQ   2048
#define BATCH   2
#define NHEAD   16
#define HDIM    128
#define FFDIM   4096
#define NTOK    4096  // B*T

using bf16_t = __bf16;
typedef __attribute__((ext_vector_type(8))) __bf16 bf16x8;
typedef __attribute__((ext_vector_type(4))) __bf16 bf16x4;
typedef __attribute__((ext_vector_type(4))) float  f32x4;

typedef __attribute__((address_space(1))) void as1_void;
typedef __attribute__((address_space(3))) void as3_void;

// async global->LDS, 16B per lane; LDS dest is wave-uniform base + lane*16
__device__ __forceinline__ void async_copy16(const void* g, void* lds) {
  __builtin_amdgcn_global_load_lds((as1_void*)(uintptr_t)g,
                                   (as3_void*)(uint32_t)(uintptr_t)lds,
                                   16, 0, 0);
}

// Packed tile layout for GEMM operands: [n>>7][k>>5][chunk=kg*128+m][8 elems]
// (chunk order == GEMM LDS layout, so staging is a linear 8KB copy.)
__device__ __forceinline__ size_t packidx(int n, int kc, int nkt) {
  // kc = 8-elem chunk index within the row's K dimension
  int kt = kc >> 2, kg = kc & 3;
  return (((size_t)(n >> 7) * nkt + kt) << 9) + (kg << 7) + (n & 127);
}

// ------------- all 5 weight fp32->bf16 conversions + packing, ONE kernel -------------
// chunk counts (8 elems each)
#define NQ 1572864   // qkv  6144x2048
#define NO 524288    // o    2048x2048
#define NG 1048576   // gate 4096x2048
#define NU 1048576   // up   4096x2048
#define ND 1048576   // down 2048x4096
#define TOTC (NQ + NO + NG + NU + ND)
__global__ __launch_bounds__(256) void f2b_all_kernel(
    const float* __restrict__ s0, const float* __restrict__ s1,
    const float* __restrict__ s2, const float* __restrict__ s3,
    const float* __restrict__ s4,
    bf16_t* __restrict__ d0, bf16_t* __restrict__ d1,
    bf16_t* __restrict__ dgu, bf16_t* __restrict__ d4) {
  int c = blockIdx.x * 256 + threadIdx.x;
  const int stride = gridDim.x * 256;
  for (; c < TOTC; c += stride) {
    const float* src; bf16_t* dst; size_t didx; int sf4;
    if (c < NQ) {                       // qkv: K=2048, nkt=64
      int n = c >> 8, kc = c & 255;
      src = s0; sf4 = n * 512 + kc * 2;
      dst = d0; didx = packidx(n, kc, 64);
    } else if (c < NQ + NO) {           // o: K=2048
      int lc = c - NQ, n = lc >> 8, kc = lc & 255;
      src = s1; sf4 = n * 512 + kc * 2;
      dst = d1; didx = packidx(n, kc, 64);
    } else if (c < NQ + NO + NG) {      // gate -> interleaved n'
      int lc = c - NQ - NO, g = lc >> 8, kc = lc & 255;
      int n2 = ((g >> 4) << 5) + (g & 15);
      src = s2; sf4 = g * 512 + kc * 2;
      dst = dgu; didx = packidx(n2, kc, 64);
    } else if (c < NQ + NO + NG + NU) { // up -> interleaved n'
      int lc = c - NQ - NO - NG, u = lc >> 8, kc = lc & 255;
      int n2 = ((u >> 4) << 5) + 16 + (u & 15);
      src = s3; sf4 = u * 512 + kc * 2;
      dst = dgu; didx = packidx(n2, kc, 64);
    } else {                            // down: K=4096, nkt=128
      int lc = c - NQ - NO - NG - NU, n = lc >> 9, kc = lc & 511;
      src = s4; sf4 = n * 1024 + kc * 2;
      dst = d4; didx = packidx(n, kc, 128);
    }
    float4 v0 = ((const float4*)src)[sf4];
    float4 v1 = ((const float4*)src)[sf4 + 1];
    bf16x8 r;
    r[0] = (bf16_t)v0.x; r[1] = (bf16_t)v0.y; r[2] = (bf16_t)v0.z; r[3] = (bf16_t)v0.w;
    r[4] = (bf16_t)v1.x; r[5] = (bf16_t)v1.y; r[6] = (bf16_t)v1.z; r[7] = (bf16_t)v1.w;
    *(bf16x8*)(dst + didx * 8) = r;
  }
}

// ------- RMSNorm * norm_w * gamma + beta -> bf16 PACKED (row = 2048, K-tiles) -------
__global__ __launch_bounds__(256) void rmsnorm_kernel(const float* __restrict__ x,
                                                      const float* __restrict__ nw,
                                                      const float* __restrict__ gamma,
                                                      const float* __restrict__ beta,
                                                      bf16_t* __restrict__ out) {
  const int row = blockIdx.x;
  const int t = threadIdx.x;
  const float* xr = x + (size_t)row * D_MODEL;
  float4 va = ((const float4*)xr)[2 * t];
  float4 vb = ((const float4*)xr)[2 * t + 1];
  float ss = va.x*va.x + va.y*va.y + va.z*va.z + va.w*va.w
           + vb.x*vb.x + vb.y*vb.y + vb.z*vb.z + vb.w*vb.w;
#pragma unroll
  for (int off = 1; off < 64; off <<= 1) ss += __shfl_xor(ss, off, 64);
  __shared__ float sred[4];
  if ((t & 63) == 0) sred[t >> 6] = ss;
  __syncthreads();
  float tot = sred[0] + sred[1] + sred[2] + sred[3];
  float inv = rsqrtf(tot * (1.0f / D_MODEL) + 1.1920929e-07f);
  const int c0 = t * 8;
  float a8[8] = {va.x, va.y, va.z, va.w, vb.x, vb.y, vb.z, vb.w};
  bf16x8 r;
#pragma unroll
  for (int j = 0; j < 8; ++j)
    r[j] = (bf16_t)(a8[j] * inv * nw[c0 + j] * gamma[c0 + j] + beta[c0 + j]);
  *(bf16x8*)(out + packidx(row, t, 64) * 8) = r;
}

// ---------------- GEMM: C(M,N) = A(M,K) @ Bw(N,K)^T, bf16 MFMA ----------------
// A, Bw in PACKED tile layout -> staging is a linear coalesced 8KB stream/tile.
// 128x128 tile, BK=32, double-buffered LDS, ONE barrier per K-iter.
// EPI: 0 = store bf16 row-major; 1 = +aux(fp32) -> fp32 row-major;
//      4 = fused silu(gate)*up -> bf16 PACKED for the down GEMM (nkt=128)
template <int EPI>
__global__ __launch_bounds__(256) void gemm_kernel(const bf16_t* __restrict__ A,
                                                   const bf16_t* __restrict__ Bw,
                                                   int M, int N, int K,
                                                   void* out, const void* aux) {
  __shared__ alignas(16) bf16_t As[2][4][128][8];  // 2 x 8KB
  __shared__ alignas(16) bf16_t Bs[2][4][128][8];
  const int tid = threadIdx.x;
  const int wave = tid >> 6, lane = tid & 63;
  const int quad = lane >> 4, l16 = lane & 15;
  const int bx = blockIdx.x, by = blockIdx.y;
  const int wr = (wave >> 1) * 64, wc = (wave & 1) * 64;
  const int rowA0 = by * 128, colB0 = bx * 128;

  const f32x4 fzero = {0.f, 0.f, 0.f, 0.f};
  f32x4 acc[4][4];
#pragma unroll
  for (int i = 0; i < 4; ++i)
#pragma unroll
    for (int j = 0; j < 4; ++j) acc[i][j] = fzero;

  const int nk = K >> 5;
  // packed tile bases; thread stages chunks tid and tid+256 (16B each)
  const bf16_t* a0 = A + ((size_t)by * nk << 12) + tid * 8;
  const bf16_t* a1 = a0 + 2048;
  const bf16_t* b0 = Bw + ((size_t)bx * nk << 12) + tid * 8;
  const bf16_t* b1 = b0 + 2048;
  char* ldsA0 = (char*)As + (wave * 64) * 16;         // + buf*8192
  char* ldsA1 = (char*)As + (256 + wave * 64) * 16;
  char* ldsB0 = (char*)Bs + (wave * 64) * 16;
  char* ldsB1 = (char*)Bs + (256 + wave * 64) * 16;

  // prologue: loads for kt=0 into buf 0
  async_copy16(a0, ldsA0);
  async_copy16(a1, ldsA1);
  async_copy16(b0, ldsB0);
  async_copy16(b1, ldsB1);
  a0 += 4096; a1 += 4096; b0 += 4096; b1 += 4096;

  for (int kt = 0; kt < nk; ++kt) {
    __syncthreads();  // drains loads for buf[cur], issued one compute-phase ago
    const int cur = kt & 1;
    if (kt + 1 < nk) {
      const int nxt = 8192 * (1 - cur);
      async_copy16(a0, ldsA0 + nxt);
      async_copy16(a1, ldsA1 + nxt);
      async_copy16(b0, ldsB0 + nxt);
      async_copy16(b1, ldsB1 + nxt);
      a0 += 4096; a1 += 4096; b0 += 4096; b1 += 4096;
    }
    bf16x8 af[4], bfr[4];
#pragma unroll
    for (int mi = 0; mi < 4; ++mi)
      af[mi] = *(const bf16x8*)&As[cur][quad][wr + mi * 16 + l16][0];
#pragma unroll
    for (int ni = 0; ni < 4; ++ni)
      bfr[ni] = *(const bf16x8*)&Bs[cur][quad][wc + ni * 16 + l16][0];
#pragma unroll
    for (int mi = 0; mi < 4; ++mi)
#pragma unroll
      for (int ni = 0; ni < 4; ++ni)
        acc[mi][ni] = __builtin_amdgcn_mfma_f32_16x16x32_bf16(af[mi], bfr[ni],
                                                              acc[mi][ni], 0, 0, 0);
  }

  // epilogue: C row = quad*4+reg, col = l16 (m89-verified)
  if (EPI == 4) {
    // ni even = gate, ni odd = up for the same 16 ff cols; write PACKED (nkt=128)
#pragma unroll
    for (int mi = 0; mi < 4; ++mi) {
#pragma unroll
      for (int r = 0; r < 4; ++r) {
        const int row = rowA0 + wr + mi * 16 + quad * 4 + r;
        const int rt = row >> 7, m = row & 127;
#pragma unroll
        for (int p = 0; p < 2; ++p) {
          float g = acc[mi][2 * p][r];
          float u = acc[mi][2 * p + 1][r];
          float sv = g / (1.0f + __expf(-g));
          const int ffcol = bx * 64 + (wc >> 1) + l16 + p * 16;
          const int kt2 = ffcol >> 5, kg2 = (ffcol >> 3) & 3, e = ffcol & 7;
          const size_t idx =
              (((((size_t)rt * 128 + kt2) << 9) + (kg2 << 7) + m) << 3) + e;
          ((bf16_t*)out)[idx] = (bf16_t)(sv * u);
        }
      }
    }
  } else {
#pragma unroll
    for (int mi = 0; mi < 4; ++mi) {
#pragma unroll
      for (int r = 0; r < 4; ++r) {
        const int row = rowA0 + wr + mi * 16 + quad * 4 + r;
        const size_t base = (size_t)row * N;
#pragma unroll
        for (int ni = 0; ni < 4; ++ni) {
          const int col = colB0 + wc + ni * 16 + l16;
          const size_t idx = base + col;
          float v = acc[mi][ni][r];
          if (EPI == 0) {
            ((bf16_t*)out)[idx] = (bf16_t)v;
          } else {
            ((float*)out)[idx] = v + ((const float*)aux)[idx];
          }
        }
      }
    }
  }
}

// ---------------- V transpose: qkv_b V-part -> vt[bh][d][t] ----------------
__global__ __launch_bounds__(256) void vtrans_kernel(const bf16_t* __restrict__ qkv,
                                                     bf16_t* __restrict__ vt) {
  const int bh = blockIdx.y;
  const int b = bh >> 4, h = bh & 15;
  const int t0 = blockIdx.x << 6;
  const int tid = threadIdx.x;
  __shared__ bf16_t tile[64][136];  // pad 8 el: row stride 272B == 4 banks offset
#pragma unroll
  for (int r = 0; r < 4; ++r) {
    int ci = r * 256 + tid;
    int t = ci >> 4, dc = ci & 15;
    bf16x8 v = *(const bf16x8*)(qkv + (size_t)(b * T_SEQ + t0 + t) * 6144 + 4096 +
                                h * HDIM + dc * 8);
    *(bf16x8*)&tile[t][dc * 8] = v;
  }
  __syncthreads();
#pragma unroll
  for (int r = 0; r < 4; ++r) {
    int ci = r * 256 + tid;
    int d = ci >> 3, ts = ci & 7;
    bf16x8 o;
#pragma unroll
    for (int j = 0; j < 8; ++j) o[j] = tile[ts * 8 + j][d];
    *(bf16x8*)(vt + ((size_t)bh * HDIM + d) * T_SEQ + t0 + ts * 8) = o;
  }
}

// ---------------- causal flash attention, 64-row Q tile, 4 waves ----------------
// qkv: [b][t][i*2048 + h*128 + d]; vt: [bh][d][t]; out: PACKED (o-proj A, nkt=64)
// v3: defer-max softmax (THR=8, T13) + per-lane partial-l accumulation.
// Common path has ZERO cross-lane shuffles and no O-rescale; the 4-deep
// ds_swizzle reduce chains (32/iter in v2) run only on the rare max-growth
// iteration (wave-uniform branch).
__global__ __launch_bounds__(256) void attn_kernel(const bf16_t* __restrict__ qkv,
                                                   const bf16_t* __restrict__ vt,
                                                   bf16_t* __restrict__ out) {
  const int bh = blockIdx.y;
  const int b = bh >> 4, h = bh & 15;
  const int qt = gridDim.x - 1 - blockIdx.x;  // big tiles dispatch first
  const int q0 = qt << 6;
  const int tid = threadIdx.x;
  const int wave = tid >> 6, lane = tid & 63;
  const int quad = lane >> 4, l16 = lane & 15;

  // K tile: 16B chunks, chunk(t,c) at index t*16 + (c ^ (t&15))   (c = d>>3)
  __shared__ alignas(16) bf16_t Ks[2][64 * 128];
  // V^T tile: chunk(d,tc) at index d*8 + (tc ^ (d&7))             (tc = t>>3)
  __shared__ alignas(16) bf16_t VTs[2][128 * 64];
  // P per wave: [16 rows][68] (136B stride: writes hit 4 disjoint 32B windows)
  __shared__ bf16_t Ps[4][16][68];

  // Q fragments straight from global (one-time)
  const size_t qbase = (size_t)(b * T_SEQ + q0 + wave * 16 + l16) * 6144 + h * HDIM;
  bf16x8 qf[4];
#pragma unroll
  for (int kk = 0; kk < 4; ++kk)
    qf[kk] = *(const bf16x8*)(qkv + qbase + kk * 32 + quad * 8);

  // staging source pointers (per-lane), advanced one K-tile per stage
  const bf16_t* gK[4];
  const bf16_t* gV[4];
#pragma unroll
  for (int c = 0; c < 4; ++c) {
    int ci = c * 256 + tid;
    int t = ci >> 4, dcs = ci & 15;
    int dc = dcs ^ (t & 15);
    gK[c] = qkv + (size_t)(b * T_SEQ + t) * 6144 + 2048 + h * HDIM + dc * 8;
    int d = ci >> 3, tcs = ci & 7;
    int tc = tcs ^ (d & 7);
    gV[c] = vt + ((size_t)bh * HDIM + d) * T_SEQ + tc * 8;
  }
  char* ldsK = (char*)Ks + wave * 1024;  // + buf*16384 + c*4096
  char* ldsV = (char*)VTs + wave * 1024;

  auto stage = [&](int buf) {
#pragma unroll
    for (int c = 0; c < 4; ++c) {
      async_copy16(gK[c], ldsK + buf * 16384 + c * 4096);
      gK[c] += 64 * 6144;
    }
#pragma unroll
    for (int c = 0; c < 4; ++c) {
      async_copy16(gV[c], ldsV + buf * 16384 + c * 4096);
      gV[c] += 64;
    }
  };

  const f32x4 fzero = {0.f, 0.f, 0.f, 0.f};
  f32x4 o[8];
#pragma unroll
  for (int i = 0; i < 8; ++i) o[i] = fzero;
  float mrow[4]  = {-3.0e38f, -3.0e38f, -3.0e38f, -3.0e38f};
  float lpart[4] = {0.f, 0.f, 0.f, 0.f};  // per-lane partial row-sum

  const float sc = 0.08838834764831845f;  // 1/sqrt(128)
  const float THR = 8.0f;                 // defer-max threshold (P <= e^8)
  const int ktmax = qt;

  // prologue: stage tile 0 into buf 0
  stage(0);

  for (int kt = 0; kt <= ktmax; ++kt) {
    const int cur = kt & 1;
    // barrier: (a) implicit vmcnt(0) drains buf[cur] loads issued last iter;
    // (b) all waves done reading buf[1-cur] from previous compute phase.
    __syncthreads();
    if (kt < ktmax) stage(1 - cur);  // in flight under this iter's compute

    const bf16_t* Kc = &Ks[cur][0];
    const bf16_t* Vc = &VTs[cur][0];

    // S = Q @ K^T (wave strip: 16 q-rows x 64 k-cols)
    f32x4 s[4];
#pragma unroll
    for (int nt = 0; nt < 4; ++nt) {
      s[nt] = fzero;
#pragma unroll
      for (int kk = 0; kk < 4; ++kk) {
        int tK = nt * 16 + l16;
        int cK = kk * 4 + quad;
        bf16x8 kf = *(const bf16x8*)(Kc + (tK * 16 + (cK ^ l16)) * 8);
        s[nt] = __builtin_amdgcn_mfma_f32_16x16x32_bf16(qf[kk], kf, s[nt], 0, 0, 0);
      }
    }

    const int qr0 = q0 + wave * 16 + quad * 4;
    const bool diag = (kt == ktmax);
    // scale + causal mask + per-lane per-row partial max (in-register, no shfl)
    float pmax[4];
#pragma unroll
    for (int r = 0; r < 4; ++r) {
      const int qr = qr0 + r;
      float mx = -3.0e38f;
#pragma unroll
      for (int nt = 0; nt < 4; ++nt) {
        float v = s[nt][r] * sc;
        if (diag) {
          int kc = kt * 64 + nt * 16 + l16;
          v = (kc <= qr) ? v : -3.0e38f;
        }
        s[nt][r] = v;
        mx = fmaxf(mx, v);
      }
      pmax[r] = mx;
    }
    // defer-max: only rescale when some row's max grew past mrow + THR
    bool ok = (pmax[0] <= mrow[0] + THR) & (pmax[1] <= mrow[1] + THR) &
              (pmax[2] <= mrow[2] + THR) & (pmax[3] <= mrow[3] + THR);
    if (!__all(ok)) {  // wave-uniform, rare after tile 0
      float alpha[4];
#pragma unroll
      for (int r = 0; r < 4; ++r) {
        float mx = pmax[r];
#pragma unroll
        for (int off = 1; off < 16; off <<= 1) mx = fmaxf(mx, __shfl_xor(mx, off, 16));
        float mnew = fmaxf(mrow[r], mx);
        alpha[r] = __expf(mrow[r] - mnew);
        mrow[r] = mnew;
        lpart[r] *= alpha[r];
      }
#pragma unroll
      for (int i = 0; i < 8; ++i)
#pragma unroll
        for (int r = 0; r < 4; ++r) o[i][r] *= alpha[r];
    }
    // exp + per-lane partial row-sum (cross-lane sum deferred to epilogue)
#pragma unroll
    for (int r = 0; r < 4; ++r) {
#pragma unroll
      for (int nt = 0; nt < 4; ++nt) {
        float pv = __expf(s[nt][r] - mrow[r]);
        s[nt][r] = pv;
        lpart[r] += pv;
      }
    }
    // P through LDS (C-layout -> A-layout)
#pragma unroll
    for (int nt = 0; nt < 4; ++nt)
#pragma unroll
      for (int r = 0; r < 4; ++r)
        Ps[wave][quad * 4 + r][nt * 16 + l16] = (bf16_t)s[nt][r];

    // O += P @ V   (pf: 2x ds_read_b64 conflict-free; vf: swizzled b128)
#pragma unroll
    for (int kk2 = 0; kk2 < 2; ++kk2) {
      const bf16_t* prow = &Ps[wave][l16][kk2 * 32 + quad * 8];
      bf16x4 p0 = *(const bf16x4*)prow;
      bf16x4 p1 = *(const bf16x4*)(prow + 4);
      bf16x8 pf;
#pragma unroll
      for (int j = 0; j < 4; ++j) { pf[j] = p0[j]; pf[4 + j] = p1[j]; }
#pragma unroll
      for (int nt2 = 0; nt2 < 8; ++nt2) {
        int dV = nt2 * 16 + l16;
        int tcV = kk2 * 4 + quad;
        bf16x8 vf = *(const bf16x8*)(Vc + (dV * 8 + (tcV ^ (dV & 7))) * 8);
        o[nt2] = __builtin_amdgcn_mfma_f32_16x16x32_bf16(pf, vf, o[nt2], 0, 0, 0);
      }
    }
  }

  // single cross-lane row-sum reduce (was per-iteration in v2)
  float rl[4];
#pragma unroll
  for (int r = 0; r < 4; ++r) {
    float l = lpart[r];
#pragma unroll
    for (int off = 1; off < 16; off <<= 1) l += __shfl_xor(l, off, 16);
    rl[r] = 1.0f / l;
  }
#pragma unroll
  for (int nt2 = 0; nt2 < 8; ++nt2) {
#pragma unroll
    for (int r = 0; r < 4; ++r) {
      const int gt = b * T_SEQ + q0 + wave * 16 + quad * 4 + r;
      const int mt = gt >> 7, m = gt & 127;
      const int col = h * HDIM + nt2 * 16 + l16;
      const int kt2 = col >> 5, kg2 = (col >> 3) & 3, e = col & 7;
      const size_t idx = (((((size_t)mt * 64 + kt2) << 9) + (kg2 << 7) + m) << 3) + e;
      out[idx] = (bf16_t)(o[nt2][r] * rl[r]);
    }
  }
}

extern "C" void kernel_launch(void* const* d_in, const int* in_sizes, int n_in,
                              void* d_out, int out_size, void* d_ws, size_t ws_size,
                              hipStream_t stream) {
  const float* x      = (const float*)d_in[0];
  const float* gamma  = (const float*)d_in[1];
  const float* beta   = (const float*)d_in[2];
  const float* qkv_w  = (const float*)d_in[3];
  const float* o_w    = (const float*)d_in[4];
  const float* gate_w = (const float*)d_in[5];
  const float* up_w   = (const float*)d_in[6];
  const float* down_w = (const float*)d_in[7];
  const float* n1w    = (const float*)d_in[8];
  const float* n2w    = (const float*)d_in[9];
  float* out = (float*)d_out;

  char* p = (char*)d_ws;
  bf16_t* qkv_wb  = (bf16_t*)p; p += (size_t)3 * D_MODEL * D_MODEL * 2;
  bf16_t* o_wb    = (bf16_t*)p; p += (size_t)D_MODEL * D_MODEL * 2;
  bf16_t* gu_wb   = (bf16_t*)p; p += (size_t)2 * FFDIM * D_MODEL * 2;  // interleaved+packed
  bf16_t* down_wb = (bf16_t*)p; p += (size_t)D_MODEL * FFDIM * 2;
  bf16_t* h_b     = (bf16_t*)p; p += (size_t)NTOK * D_MODEL * 2;   // packed; reused for h2
  bf16_t* qkv_b   = (bf16_t*)p; p += (size_t)NTOK * 3 * D_MODEL * 2;
  bf16_t* attn_b  = (bf16_t*)p; p += (size_t)NTOK * D_MODEL * 2;   // packed
  float*  x1      = (float*)p;  p += (size_t)NTOK * D_MODEL * 4;
  bf16_t* g_b     = (bf16_t*)p; p += (size_t)NTOK * FFDIM * 2;     // packed silu(g)*u
  bf16_t* vt_b    = g_b;  // V^T overlaps g_b: lifetimes disjoint (attn vs FFN phase)

  dim3 blk(256);
  // all weight conversions + packing in one launch
  f2b_all_kernel<<<dim3(2048), blk, 0, stream>>>(
      qkv_w, o_w, gate_w, up_w, down_w,
      qkv_wb, o_wb, gu_wb, down_wb);

  // attention sub-block
  rmsnorm_kernel<<<dim3(NTOK), blk, 0, stream>>>(x, n1w, gamma, beta, h_b);
  gemm_kernel<0><<<dim3(3 * D_MODEL / 128, NTOK / 128), blk, 0, stream>>>(
      h_b, qkv_wb, NTOK, 3 * D_MODEL, D_MODEL, qkv_b, nullptr);
  vtrans_kernel<<<dim3(T_SEQ / 64, BATCH * NHEAD), blk, 0, stream>>>(qkv_b, vt_b);
  attn_kernel<<<dim3(T_SEQ / 64, BATCH * NHEAD), blk, 0, stream>>>(qkv_b, vt_b, attn_b);
  gemm_kernel<1><<<dim3(D_MODEL / 128, NTOK / 128), blk, 0, stream>>>(
      attn_b, o_wb, NTOK, D_MODEL, D_MODEL, x1, x);

  // FFN sub-block (gate+up fused into one GEMM, N=8192 interleaved)
  rmsnorm_kernel<<<dim3(NTOK), blk, 0, stream>>>(x1, n2w, gamma, beta, h_b);
  gemm_kernel<4><<<dim3(2 * FFDIM / 128, NTOK / 128), blk, 0, stream>>>(
      h_b, gu_wb, NTOK, 2 * FFDIM, D_MODEL, g_b, nullptr);
  gemm_kernel<1><<<dim3(D_MODEL / 128, NTOK / 128), blk, 0, stream>>>(
      g_b, down_wb, NTOK, D_MODEL, FFDIM, out, x1);
}